// Round 4
// baseline (1007.984 us; speedup 1.0000x reference)
//
#include <hip/hip_runtime.h>
#include <hip/hip_bf16.h>
#include <stdint.h>

#define B_    2
#define S_    4096
#define H_    16
#define NOPE  128
#define ROPE  64
#define QKD   192
#define VD    128
#define R_    512
#define KERW  32
#define STRW  16
#define NBLK  255
#define NSEL  64
#define TOPKN 16
#define SCALEF 0.07216878364870323f
#define BIGF   1000000000.0f

typedef __attribute__((ext_vector_type(8))) short bf8_t;   // 8 bf16 (4 VGPRs)
typedef __attribute__((ext_vector_type(4))) float f4_t;    // MFMA acc

#define MFB(a,b,c) __builtin_amdgcn_mfma_f32_16x16x32_bf16((a),(b),(c),0,0,0)

__device__ inline unsigned short f2bf(float x) {
    __hip_bfloat16 b = __float2bfloat16(x);
    return *reinterpret_cast<unsigned short*>(&b);
}
// 3-way bf16 split: x ~= a + b + c with residual ~2^-26 rel
__device__ inline void split3f(float x, unsigned short& a, unsigned short& b,
                               unsigned short& c) {
    __hip_bfloat16 b0 = __float2bfloat16(x);
    float f0 = __bfloat162float(b0);
    float r1 = x - f0;
    __hip_bfloat16 b1 = __float2bfloat16(r1);
    float f1 = __bfloat162float(b1);
    float r2 = r1 - f1;
    __hip_bfloat16 b2 = __float2bfloat16(r2);
    a = *reinterpret_cast<unsigned short*>(&b0);
    b = *reinterpret_cast<unsigned short*>(&b1);
    c = *reinterpret_cast<unsigned short*>(&b2);
}

// ---------------------------------------------------------------------------
// G1: cmp_kv = window(kv_lora) @ W_cmp_kv   (M=510, N=512, K=16384)
// Tile 128x64, split-K=16, atomicAdd epilogue (out pre-zeroed).  (unchanged)
// ---------------------------------------------------------------------------
__global__ __launch_bounds__(256) void g1_cmpkv(const float* __restrict__ A,
                                                const float* __restrict__ W,
                                                float* __restrict__ out) {
    __shared__ float As[16][132];
    __shared__ float Bs[16][68];
    const int t  = threadIdx.x;
    const int m0 = blockIdx.x * 128;
    const int n0 = blockIdx.y * 64;
    const int k0 = blockIdx.z * 1024;
    const int tr = t >> 4, tc = t & 15;
    float acc[8][4];
#pragma unroll
    for (int i = 0; i < 8; ++i)
#pragma unroll
        for (int j = 0; j < 4; ++j) acc[i][j] = 0.f;

    for (int kt = 0; kt < 1024; kt += 16) {
        __syncthreads();
#pragma unroll
        for (int i = 0; i < 2; ++i) {
            int f = t + i * 256;
            int r = f >> 2, kq = (f & 3) * 4;
            int m = m0 + r;
            float4 av = make_float4(0.f, 0.f, 0.f, 0.f);
            if (m < 510) {
                int b = (m >= NBLK) ? 1 : 0;
                int n = m - b * NBLK;
                av = *(const float4*)(A + (size_t)(b * S_ + n * STRW) * R_ + k0 + kt + kq);
            }
            As[kq + 0][r] = av.x; As[kq + 1][r] = av.y;
            As[kq + 2][r] = av.z; As[kq + 3][r] = av.w;
        }
        {
            int kb = t >> 4, nq = (t & 15) * 4;
            *(float4*)&Bs[kb][nq] =
                *(const float4*)(W + (size_t)(k0 + kt + kb) * R_ + n0 + nq);
        }
        __syncthreads();
#pragma unroll
        for (int kk = 0; kk < 16; ++kk) {
            float a0[8], b0[4];
            float4 x = *(const float4*)&As[kk][8 * tr];
            float4 y = *(const float4*)&As[kk][8 * tr + 4];
            a0[0] = x.x; a0[1] = x.y; a0[2] = x.z; a0[3] = x.w;
            a0[4] = y.x; a0[5] = y.y; a0[6] = y.z; a0[7] = y.w;
            float4 z = *(const float4*)&Bs[kk][4 * tc];
            b0[0] = z.x; b0[1] = z.y; b0[2] = z.z; b0[3] = z.w;
#pragma unroll
            for (int i = 0; i < 8; ++i)
#pragma unroll
                for (int j = 0; j < 4; ++j)
                    acc[i][j] = fmaf(a0[i], b0[j], acc[i][j]);
        }
    }
#pragma unroll
    for (int i = 0; i < 8; ++i) {
        int m = m0 + 8 * tr + i;
        if (m < 510) {
#pragma unroll
            for (int j = 0; j < 4; ++j)
                atomicAdd(&out[(size_t)m * R_ + n0 + 4 * tc + j], acc[i][j]);
        }
    }
}

// ---------------------------------------------------------------------------
// G1b: cmp_pe = window(k_pe) @ W_cmp_kpe   (unchanged)
// ---------------------------------------------------------------------------
__global__ __launch_bounds__(256) void g1b_cmppe(const float* __restrict__ A,
                                                 const float* __restrict__ W,
                                                 float* __restrict__ out) {
    const int t = threadIdx.x;
    const int m = blockIdx.x * 4 + (t >> 6);
    const int col = t & 63;
    if (m >= 510) return;
    const int b = (m >= NBLK) ? 1 : 0;
    const int n = m - b * NBLK;
    const float* arow = A + (size_t)(b * S_ + n * STRW) * ROPE;
    float acc = 0.f;
    for (int k = 0; k < 2048; k += 4) {
        float4 a4 = *(const float4*)(arow + k);
        acc = fmaf(a4.x, W[(size_t)(k + 0) * 64 + col], acc);
        acc = fmaf(a4.y, W[(size_t)(k + 1) * 64 + col], acc);
        acc = fmaf(a4.z, W[(size_t)(k + 2) * 64 + col], acc);
        acc = fmaf(a4.w, W[(size_t)(k + 3) * 64 + col], acc);
    }
    out[(size_t)m * 64 + col] = acc;
}

// ---------------------------------------------------------------------------
// G2: kvb = cmp_kv @ W_kv_b; epilogue writes K as 3 bf16 planes + vT bf16.
// (unchanged)
// ---------------------------------------------------------------------------
__global__ __launch_bounds__(256) void g2_kvb(const float* __restrict__ A,
                                              const float* __restrict__ W,
                                              unsigned short* __restrict__ kh_g,
                                              unsigned short* __restrict__ km_g,
                                              unsigned short* __restrict__ kl_g,
                                              unsigned short* __restrict__ vT_g) {
    __shared__ float As[16][68];
    __shared__ float Bs[16][68];
    const int t  = threadIdx.x;
    const int m0 = blockIdx.x * 64;
    const int n0 = blockIdx.y * 64;
    const int tr = t >> 4, tc = t & 15;
    float acc[4][4];
#pragma unroll
    for (int i = 0; i < 4; ++i)
#pragma unroll
        for (int j = 0; j < 4; ++j) acc[i][j] = 0.f;

    for (int kt = 0; kt < R_; kt += 16) {
        __syncthreads();
        {
            int r = t >> 2, kq = (t & 3) * 4;
            int m = m0 + r;
            float4 av = make_float4(0.f, 0.f, 0.f, 0.f);
            if (m < 510) av = *(const float4*)(A + (size_t)m * R_ + kt + kq);
            As[kq + 0][r] = av.x; As[kq + 1][r] = av.y;
            As[kq + 2][r] = av.z; As[kq + 3][r] = av.w;
        }
        {
            int kb = t >> 4, nq = (t & 15) * 4;
            *(float4*)&Bs[kb][nq] =
                *(const float4*)(W + (size_t)(kt + kb) * 4096 + n0 + nq);
        }
        __syncthreads();
#pragma unroll
        for (int kk = 0; kk < 16; ++kk) {
            float4 x = *(const float4*)&As[kk][4 * tr];
            float4 z = *(const float4*)&Bs[kk][4 * tc];
            float a0[4] = {x.x, x.y, x.z, x.w};
            float b0[4] = {z.x, z.y, z.z, z.w};
#pragma unroll
            for (int i = 0; i < 4; ++i)
#pragma unroll
                for (int j = 0; j < 4; ++j)
                    acc[i][j] = fmaf(a0[i], b0[j], acc[i][j]);
        }
    }
#pragma unroll
    for (int i = 0; i < 4; ++i) {
        int m = m0 + 4 * tr + i;
        if (m < 510) {
            int b = (m >= NBLK) ? 1 : 0;
            int n = m - b * NBLK;
#pragma unroll
            for (int j = 0; j < 4; ++j) {
                int c = n0 + 4 * tc + j;
                int h = c >> 8, jj = c & 255;
                size_t bh = (size_t)(b * H_ + h);
                float x = acc[i][j];
                if (jj < NOPE) {
                    size_t idx = (bh * NBLK + n) * QKD + jj;
                    unsigned short u0, u1, u2;
                    split3f(x, u0, u1, u2);
                    kh_g[idx] = u0; km_g[idx] = u1; kl_g[idx] = u2;
                } else {
                    vT_g[(bh * VD + (jj - NOPE)) * 256 + n] = f2bf(x);
                }
            }
        }
    }
}

// G2b: rope part into K planes (d = 128..191), split3 per element. (unchanged)
__global__ void g2b_pefill(const float* __restrict__ cmp_pe,
                           unsigned short* __restrict__ kh_g,
                           unsigned short* __restrict__ km_g,
                           unsigned short* __restrict__ kl_g) {
    int gid = blockIdx.x * 256 + threadIdx.x;   // 522240 total, exact
    int rr = gid & 63;
    int rest = gid >> 6;
    int n = rest % NBLK;
    int bh = rest / NBLK;
    int b = bh >> 4;
    float x = cmp_pe[((size_t)(b * NBLK + n)) * ROPE + rr];
    size_t idx = ((size_t)bh * NBLK + n) * QKD + NOPE + rr;
    unsigned short u0, u1, u2;
    split3f(x, u0, u1, u2);
    kh_g[idx] = u0; km_g[idx] = u1; kl_g[idx] = u2;
}

// ---------------------------------------------------------------------------
// G3 v2: MFMA attention, 2 blocks/CU.
// LDS 69.8 KB total:
//   [0      .. 33024)  sc fp32 [32][258]        (score accum; later vT overlay)
//   [33024  .. 71424)  kst 3x[32][200] ushort    (Q planes then K-chunk planes)
//   [0      .. 34816)  vTl [128][136] ushort     (PV phase, overlays sc)
//   [36864  .. 53760)  scb [32][264] ushort      (probs bf16, overlays kst)
// Q A-fragments live in registers (9 bf8 = 36 VGPR).  K-dim 192 split across
// wave pairs (96 each); partials combined via ds_add_f32 into zeroed sc.
// Waves: score (mt=w&1, nt=(w>>1)&1, khf=w>>2); PV (mt2=w&1, jtp=w>>1).
// __launch_bounds__(512,4): cap VGPR at 128 to hold 2 blocks/CU residency.
// ---------------------------------------------------------------------------
__global__ __launch_bounds__(512, 4) void g3_attn(const float* __restrict__ q,
                                               const unsigned short* __restrict__ kh_g,
                                               const unsigned short* __restrict__ km_g,
                                               const unsigned short* __restrict__ kl_g,
                                               const unsigned short* __restrict__ vT_g,
                                               float* __restrict__ o,
                                               unsigned int* __restrict__ p_agg) {
    __shared__ __attribute__((aligned(16))) char smem[71424];
    float* sc           = (float*)smem;                        // [32][258]
    unsigned short* kst = (unsigned short*)(smem + 33024);     // 3x[32][200]
    unsigned short* vTl = (unsigned short*)smem;               // [128][136]
    unsigned short* scb = (unsigned short*)(smem + 36864);     // [32][264]

    const int t  = threadIdx.x;
    const int s0 = blockIdx.x * 32;
    const int bh = blockIdx.y;
    const int b = bh >> 4, h = bh & 15;
    const int wv = t >> 6, lane = t & 63;
    const int ln = lane & 15, quad = lane >> 4;

    // ---- zero sc (accumulated via ds_add_f32) ----
    for (int f = t; f < 8256; f += 512) sc[f] = 0.f;

    // ---- stage Q (32x192 fp32 -> 3 bf16 planes in kst, stride 200) ----
    for (int f = t; f < 1536; f += 512) {
        int r = f / 48, c4 = (f % 48) * 4;
        float4 v = *(const float4*)(q + ((size_t)(b * S_ + s0 + r) * H_ + h) * QKD + c4);
        ushort4 uh, um, ul;
        split3f(v.x, uh.x, um.x, ul.x);
        split3f(v.y, uh.y, um.y, ul.y);
        split3f(v.z, uh.z, um.z, ul.z);
        split3f(v.w, uh.w, um.w, ul.w);
        int base = r * 200 + c4;
        *(ushort4*)(kst + base)         = uh;
        *(ushort4*)(kst + 6400 + base)  = um;
        *(ushort4*)(kst + 12800 + base) = ul;
    }
    __syncthreads();

    // ---- Q fragments -> registers (this wave's 16 rows, 96-k half, 3 planes)
    const int mt = wv & 1, nt = (wv >> 1) & 1, khf = wv >> 2;
    bf8_t qf[3][3];
    {
        const unsigned short* ab = kst + (16 * mt + ln) * 200 + khf * 96 + quad * 8;
#pragma unroll
        for (int kk = 0; kk < 3; ++kk)
#pragma unroll
            for (int p = 0; p < 3; ++p)
                qf[kk][p] = *(const bf8_t*)(ab + p * 6400 + kk * 32);
    }

    // ---- score phase: 8 chunks of 32 K-rows ----
    for (int c = 0; c < 8; ++c) {
        __syncthreads();   // frag reads / prev chunk done before restaging
        for (int f = t; f < 2304; f += 512) {
            int p = f / 768, rem = f - p * 768;
            int row = rem / 24, seg = rem - row * 24;
            int gn = c * 32 + row;
            const unsigned short* src = (p == 0) ? kh_g : (p == 1) ? km_g : kl_g;
            uint4 val = make_uint4(0, 0, 0, 0);
            if (gn < NBLK)
                val = *(const uint4*)(src + ((size_t)(bh * NBLK + gn)) * QKD + seg * 8);
            *(uint4*)(kst + p * 6400 + row * 200 + seg * 8) = val;
        }
        __syncthreads();
        f4_t acc = {0.f, 0.f, 0.f, 0.f};
        const unsigned short* bb = kst + (16 * nt + ln) * 200 + khf * 96 + quad * 8;
#pragma unroll
        for (int kk = 0; kk < 3; ++kk) {
            bf8_t bhf = *(const bf8_t*)(bb + kk * 32);
            bf8_t bmf = *(const bf8_t*)(bb + 6400 + kk * 32);
            bf8_t blf = *(const bf8_t*)(bb + 12800 + kk * 32);
            acc = MFB(qf[kk][0], bhf, acc);
            acc = MFB(qf[kk][0], bmf, acc);
            acc = MFB(qf[kk][1], bhf, acc);
            acc = MFB(qf[kk][0], blf, acc);
            acc = MFB(qf[kk][1], bmf, acc);
            acc = MFB(qf[kk][2], bhf, acc);
        }
        int col = c * 32 + 16 * nt + ln;
        int row0 = 16 * mt + 4 * quad;
#pragma unroll
        for (int r = 0; r < 4; ++r)
            atomicAdd(&sc[(row0 + r) * 258 + col], acc[r] * SCALEF);
    }
    __syncthreads();

    // ---- softmax (fp32, 16 threads/row) -> p_agg (fp32) + scb (bf16) ----
    {
        int r = t >> 4, g = t & 15;
        int s = s0 + r;
        int nv = (s >= 31) ? (((s - 31) >> 4) + 1) : 0;
        float m = -INFINITY;
        for (int n = g; n < nv; n += 16) m = fmaxf(m, sc[r * 258 + n]);
#pragma unroll
        for (int off = 1; off < 16; off <<= 1) m = fmaxf(m, __shfl_xor(m, off, 16));
        float sum = 0.f;
        for (int n = g; n < nv; n += 16) {
            float p = __expf(sc[r * 258 + n] - m);
            sc[r * 258 + n] = p;
            sum += p;
        }
#pragma unroll
        for (int off = 1; off < 16; off <<= 1) sum += __shfl_xor(sum, off, 16);
        float inv = (nv > 0) ? (1.0f / sum) : 0.f;
        unsigned int* pa = p_agg + (size_t)(b * S_ + s) * NBLK;
        for (int n = g; n < 256; n += 16) {
            float p = (n < nv) ? sc[r * 258 + n] * inv : 0.f;
            scb[r * 264 + n] = f2bf(p);
            if (n < nv) atomicMax(&pa[n], __float_as_uint(p));
        }
    }
    __syncthreads();   // sc dead after this; vTl may overlay it

    // ---- PV: O(32x128) = P(32x255) @ V, two 128-k halves ----
    const int mt2 = wv & 1, jtp = wv >> 1;
    f4_t oa0 = {0.f, 0.f, 0.f, 0.f}, oa1 = oa0;
    for (int kh2 = 0; kh2 < 2; ++kh2) {
        for (int f = t; f < 2048; f += 512) {
            int j = f >> 4, seg = f & 15;
            *(uint4*)(vTl + j * 136 + seg * 8) =
                *(const uint4*)(vT_g + ((size_t)(bh * VD + j)) * 256 + kh2 * 128 + seg * 8);
        }
        __syncthreads();
        const unsigned short* pab = scb + (16 * mt2 + ln) * 264 + kh2 * 128 + quad * 8;
        const unsigned short* v0 = vTl + (size_t)(16 * (2 * jtp) + ln) * 136 + quad * 8;
        const unsigned short* v1 = vTl + (size_t)(16 * (2 * jtp + 1) + ln) * 136 + quad * 8;
#pragma unroll
        for (int kk = 0; kk < 4; ++kk) {
            bf8_t a = *(const bf8_t*)(pab + kk * 32);
            oa0 = MFB(a, *(const bf8_t*)(v0 + kk * 32), oa0);
            oa1 = MFB(a, *(const bf8_t*)(v1 + kk * 32), oa1);
        }
        __syncthreads();   // protect vTl before restage
    }
    {
        int row0 = s0 + 16 * mt2 + 4 * quad;
#pragma unroll
        for (int r = 0; r < 4; ++r) {
            size_t rbase = (size_t)(b * S_ + row0 + r) * 2048 + h * VD;
            o[rbase + 16 * (2 * jtp) + ln] = oa0[r];
            o[rbase + 16 * (2 * jtp + 1) + ln] = oa1[r];
        }
    }
}

// ---------------------------------------------------------------------------
// G4: slc + forced/causal + top-16.  (unchanged)
// ---------------------------------------------------------------------------
__global__ __launch_bounds__(256) void g4_topk(const float* __restrict__ p_agg,
                                               float* __restrict__ outI) {
    const int gid  = blockIdx.x * 256 + threadIdx.x;
    const int w    = gid >> 6;          // = b*S + s
    const int lane = threadIdx.x & 63;  // = j
    const int s    = w & (S_ - 1);
    const float* pa = p_agg + (size_t)w * NBLK;
    const int j = lane;
    float slc = 0.f;
    int nlo = 4 * j - 1; if (nlo < 0) nlo = 0;
    int nhi = 4 * j + 3; if (nhi > NBLK - 1) nhi = NBLK - 1;
    for (int n = nlo; n <= nhi; ++n) slc += pa[n];
    const int jt = s >> 6;
    float val;
    if (j <= jt) val = ((j < 1) || (j >= jt - 1)) ? BIGF : slc;
    else         val = -BIGF;
    bool taken = false;
    float* dst = outI + (size_t)w * TOPKN;
    for (int kk = 0; kk < TOPKN; ++kk) {
        float v = taken ? -INFINITY : val;
        float m = v;
#pragma unroll
        for (int off = 32; off; off >>= 1) m = fmaxf(m, __shfl_xor(m, off, 64));
        unsigned long long msk = __ballot((!taken) && (val == m));
        int first = __ffsll(msk) - 1;
        if (lane == first) taken = true;
        if (lane == kk) dst[kk] = (m <= -BIGF * 0.5f) ? -1.0f : (float)first;
    }
}

// ---------------------------------------------------------------------------
extern "C" void kernel_launch(void* const* d_in, const int* in_sizes, int n_in,
                              void* d_out, int out_size, void* d_ws, size_t ws_size,
                              hipStream_t stream) {
    const float* q         = (const float*)d_in[0];
    const float* kv_lora   = (const float*)d_in[1];
    const float* k_pe      = (const float*)d_in[2];
    const float* W_cmp_kv  = (const float*)d_in[3];
    const float* W_cmp_kpe = (const float*)d_in[4];
    const float* W_kv_b    = (const float*)d_in[5];
    float* out = (float*)d_out;
    char* W = (char*)d_ws;

    // byte offsets (all 16-aligned)
    float* cmp_kv        = (float*)W;                         // 1,044,480 B
    float* cmp_pe        = (float*)(W + 1044480);             //   130,560 B
    unsigned int* p_agg  = (unsigned int*)(W + 1175040);      // 8,355,840 B
    unsigned short* kh_g = (unsigned short*)(W + 9530880);    // 3,133,440 B
    unsigned short* km_g = (unsigned short*)(W + 12664320);   // 3,133,440 B
    unsigned short* kl_g = (unsigned short*)(W + 15797760);   // 3,133,440 B
    unsigned short* vT_g = (unsigned short*)(W + 18931200);   // 2,097,152 B
                                                              // end 21,028,352 B

    hipMemsetAsync(cmp_kv, 0, (size_t)1044480, stream);
    hipMemsetAsync(p_agg, 0, (size_t)8355840, stream);

    g1_cmpkv  <<<dim3(4, 8, 16), 256, 0, stream>>>(kv_lora, W_cmp_kv, cmp_kv);
    g1b_cmppe <<<dim3(128),      256, 0, stream>>>(k_pe, W_cmp_kpe, cmp_pe);
    g2_kvb    <<<dim3(8, 64),    256, 0, stream>>>(cmp_kv, W_kv_b, kh_g, km_g, kl_g, vT_g);
    g2b_pefill<<<dim3(2040),     256, 0, stream>>>(cmp_pe, kh_g, km_g, kl_g);
    g3_attn   <<<dim3(128, 32),  512, 0, stream>>>(q, kh_g, km_g, kl_g, vT_g, out, p_agg);
    g4_topk   <<<dim3(2048),     256, 0, stream>>>((const float*)p_agg, out + 16777216);
}

// Round 5
// 746.940 us; speedup vs baseline: 1.3495x; 1.3495x over previous
//
#include <hip/hip_runtime.h>
#include <hip/hip_bf16.h>
#include <stdint.h>

#define B_    2
#define S_    4096
#define H_    16
#define NOPE  128
#define ROPE  64
#define QKD   192
#define VD    128
#define R_    512
#define STRW  16
#define NBLK  255
#define TOPKN 16
#define SCALEF 0.07216878364870323f
#define BIGF   1000000000.0f

typedef __attribute__((ext_vector_type(8))) _Float16 h8_t;   // 8 fp16 (4 VGPRs)
typedef __attribute__((ext_vector_type(4))) float f4_t;      // MFMA acc

#define MFH(a,b,c) __builtin_amdgcn_mfma_f32_16x16x32_f16((a),(b),(c),0,0,0)

__device__ inline unsigned short f2h(float x) {
    _Float16 hh = (_Float16)x;
    return *(unsigned short*)&hh;
}
// 2-way fp16 split: x ~= h + l, residual ~2^-22 rel
__device__ inline void split2h(float x, unsigned short& h, unsigned short& l) {
    _Float16 hh = (_Float16)x;
    _Float16 ll = (_Float16)(x - (float)hh);
    h = *(unsigned short*)&hh;
    l = *(unsigned short*)&ll;
}

// ---------------------------------------------------------------------------
// G1: cmp_kv = window(kv_lora) @ W_cmp_kv   (M=510, N=512, K=16384)
// Tile 128x64, split-K=16, atomicAdd epilogue (out pre-zeroed).  (unchanged)
// ---------------------------------------------------------------------------
__global__ __launch_bounds__(256) void g1_cmpkv(const float* __restrict__ A,
                                                const float* __restrict__ W,
                                                float* __restrict__ out) {
    __shared__ float As[16][132];
    __shared__ float Bs[16][68];
    const int t  = threadIdx.x;
    const int m0 = blockIdx.x * 128;
    const int n0 = blockIdx.y * 64;
    const int k0 = blockIdx.z * 1024;
    const int tr = t >> 4, tc = t & 15;
    float acc[8][4];
#pragma unroll
    for (int i = 0; i < 8; ++i)
#pragma unroll
        for (int j = 0; j < 4; ++j) acc[i][j] = 0.f;

    for (int kt = 0; kt < 1024; kt += 16) {
        __syncthreads();
#pragma unroll
        for (int i = 0; i < 2; ++i) {
            int f = t + i * 256;
            int r = f >> 2, kq = (f & 3) * 4;
            int m = m0 + r;
            float4 av = make_float4(0.f, 0.f, 0.f, 0.f);
            if (m < 510) {
                int b = (m >= NBLK) ? 1 : 0;
                int n = m - b * NBLK;
                av = *(const float4*)(A + (size_t)(b * S_ + n * STRW) * R_ + k0 + kt + kq);
            }
            As[kq + 0][r] = av.x; As[kq + 1][r] = av.y;
            As[kq + 2][r] = av.z; As[kq + 3][r] = av.w;
        }
        {
            int kb = t >> 4, nq = (t & 15) * 4;
            *(float4*)&Bs[kb][nq] =
                *(const float4*)(W + (size_t)(k0 + kt + kb) * R_ + n0 + nq);
        }
        __syncthreads();
#pragma unroll
        for (int kk = 0; kk < 16; ++kk) {
            float a0[8], b0[4];
            float4 x = *(const float4*)&As[kk][8 * tr];
            float4 y = *(const float4*)&As[kk][8 * tr + 4];
            a0[0] = x.x; a0[1] = x.y; a0[2] = x.z; a0[3] = x.w;
            a0[4] = y.x; a0[5] = y.y; a0[6] = y.z; a0[7] = y.w;
            float4 z = *(const float4*)&Bs[kk][4 * tc];
            b0[0] = z.x; b0[1] = z.y; b0[2] = z.z; b0[3] = z.w;
#pragma unroll
            for (int i = 0; i < 8; ++i)
#pragma unroll
                for (int j = 0; j < 4; ++j)
                    acc[i][j] = fmaf(a0[i], b0[j], acc[i][j]);
        }
    }
#pragma unroll
    for (int i = 0; i < 8; ++i) {
        int m = m0 + 8 * tr + i;
        if (m < 510) {
#pragma unroll
            for (int j = 0; j < 4; ++j)
                atomicAdd(&out[(size_t)m * R_ + n0 + 4 * tc + j], acc[i][j]);
        }
    }
}

// ---------------------------------------------------------------------------
// G1b: cmp_pe = window(k_pe) @ W_cmp_kpe   (unchanged)
// ---------------------------------------------------------------------------
__global__ __launch_bounds__(256) void g1b_cmppe(const float* __restrict__ A,
                                                 const float* __restrict__ W,
                                                 float* __restrict__ out) {
    const int t = threadIdx.x;
    const int m = blockIdx.x * 4 + (t >> 6);
    const int col = t & 63;
    if (m >= 510) return;
    const int b = (m >= NBLK) ? 1 : 0;
    const int n = m - b * NBLK;
    const float* arow = A + (size_t)(b * S_ + n * STRW) * ROPE;
    float acc = 0.f;
    for (int k = 0; k < 2048; k += 4) {
        float4 a4 = *(const float4*)(arow + k);
        acc = fmaf(a4.x, W[(size_t)(k + 0) * 64 + col], acc);
        acc = fmaf(a4.y, W[(size_t)(k + 1) * 64 + col], acc);
        acc = fmaf(a4.z, W[(size_t)(k + 2) * 64 + col], acc);
        acc = fmaf(a4.w, W[(size_t)(k + 3) * 64 + col], acc);
    }
    out[(size_t)m * 64 + col] = acc;
}

// ---------------------------------------------------------------------------
// G2: kvb = cmp_kv @ W_kv_b; epilogue writes K as 2 fp16 planes (h/l split)
// kh/kl [bh][n][192] and vT fp16 [bh][j][256] (col n=255 unwritten; P=0 there).
// ---------------------------------------------------------------------------
__global__ __launch_bounds__(256) void g2_kvb(const float* __restrict__ A,
                                              const float* __restrict__ W,
                                              unsigned short* __restrict__ kh_g,
                                              unsigned short* __restrict__ kl_g,
                                              unsigned short* __restrict__ vT_g) {
    __shared__ float As[16][68];
    __shared__ float Bs[16][68];
    const int t  = threadIdx.x;
    const int m0 = blockIdx.x * 64;
    const int n0 = blockIdx.y * 64;
    const int tr = t >> 4, tc = t & 15;
    float acc[4][4];
#pragma unroll
    for (int i = 0; i < 4; ++i)
#pragma unroll
        for (int j = 0; j < 4; ++j) acc[i][j] = 0.f;

    for (int kt = 0; kt < R_; kt += 16) {
        __syncthreads();
        {
            int r = t >> 2, kq = (t & 3) * 4;
            int m = m0 + r;
            float4 av = make_float4(0.f, 0.f, 0.f, 0.f);
            if (m < 510) av = *(const float4*)(A + (size_t)m * R_ + kt + kq);
            As[kq + 0][r] = av.x; As[kq + 1][r] = av.y;
            As[kq + 2][r] = av.z; As[kq + 3][r] = av.w;
        }
        {
            int kb = t >> 4, nq = (t & 15) * 4;
            *(float4*)&Bs[kb][nq] =
                *(const float4*)(W + (size_t)(kt + kb) * 4096 + n0 + nq);
        }
        __syncthreads();
#pragma unroll
        for (int kk = 0; kk < 16; ++kk) {
            float4 x = *(const float4*)&As[kk][4 * tr];
            float4 z = *(const float4*)&Bs[kk][4 * tc];
            float a0[4] = {x.x, x.y, x.z, x.w};
            float b0[4] = {z.x, z.y, z.z, z.w};
#pragma unroll
            for (int i = 0; i < 4; ++i)
#pragma unroll
                for (int j = 0; j < 4; ++j)
                    acc[i][j] = fmaf(a0[i], b0[j], acc[i][j]);
        }
    }
#pragma unroll
    for (int i = 0; i < 4; ++i) {
        int m = m0 + 4 * tr + i;
        if (m < 510) {
            int b = (m >= NBLK) ? 1 : 0;
            int n = m - b * NBLK;
#pragma unroll
            for (int j = 0; j < 4; ++j) {
                int c = n0 + 4 * tc + j;
                int h = c >> 8, jj = c & 255;
                size_t bh = (size_t)(b * H_ + h);
                float x = acc[i][j];
                if (jj < NOPE) {
                    size_t idx = (bh * NBLK + n) * QKD + jj;
                    unsigned short uh, ul;
                    split2h(x, uh, ul);
                    kh_g[idx] = uh; kl_g[idx] = ul;
                } else {
                    vT_g[(bh * VD + (jj - NOPE)) * 256 + n] = f2h(x);
                }
            }
        }
    }
}

// G2b: rope part into K planes (d = 128..191), split2 per element.
__global__ void g2b_pefill(const float* __restrict__ cmp_pe,
                           unsigned short* __restrict__ kh_g,
                           unsigned short* __restrict__ kl_g) {
    int gid = blockIdx.x * 256 + threadIdx.x;   // 522240 total, exact
    int rr = gid & 63;
    int rest = gid >> 6;
    int n = rest % NBLK;
    int bh = rest / NBLK;
    int b = bh >> 4;
    float x = cmp_pe[((size_t)(b * NBLK + n)) * ROPE + rr];
    size_t idx = ((size_t)bh * NBLK + n) * QKD + NOPE + rr;
    unsigned short uh, ul;
    split2h(x, uh, ul);
    kh_g[idx] = uh; kl_g[idx] = ul;
}

// ---------------------------------------------------------------------------
// G3 v3: MFMA attention, 64 Q-rows/block, scores register-resident.
// Per (b,h, 64-row tile), 512 threads (8 waves), grid (64, 32).
// Score: fp16 2-way split, 3-term MFMA emulation (hh + h*l + l*h, ~1e-7 rel).
//   Q frags direct global->reg (48 VGPR).  K staged per 64-col chunk (2 planes,
//   [64][196] each).  Wave (mt=wv&3, nhalf=wv>>2) owns rows 16mt..+15 and cols
//   {c*64 + nhalf*32 + [0,32)} -> accs[4][2] f4 in regs.  No LDS sc, no atomics.
// Softmax: in-register, cross-wave row combine via 1KB rowred buffer.
// PV: probs -> scb fp16 [64][264], V staged [128][136] x2 halves, plain f16 MFMA.
// LDS = 68608 B -> 2 blocks/CU.  __launch_bounds__(512,4) caps VGPR at 128.
// ---------------------------------------------------------------------------
__global__ __launch_bounds__(512, 4) void g3_attn(const float* __restrict__ q,
                                               const unsigned short* __restrict__ kh_g,
                                               const unsigned short* __restrict__ kl_g,
                                               const unsigned short* __restrict__ vT_g,
                                               float* __restrict__ o,
                                               unsigned int* __restrict__ p_agg) {
    __shared__ __attribute__((aligned(16))) char smem[68608];
    unsigned short* ksth = (unsigned short*)smem;            // [64][196]
    unsigned short* kstl = ksth + 12544;                     // [64][196]
    float* rowred       = (float*)(smem + 50176);            // [2][2][4][16]
    unsigned short* scb = (unsigned short*)smem;             // [64][264] (overlays kst)
    unsigned short* vTl = (unsigned short*)(smem + 33792);   // [128][136]

    const int t  = threadIdx.x;
    const int s0 = blockIdx.x * 64;
    const int bh = blockIdx.y;
    const int b = bh >> 4, h = bh & 15;
    const int wv = t >> 6, lane = t & 63;
    const int ln = lane & 15, quad = lane >> 4;
    const int mt = wv & 3, nhalf = wv >> 2;

    // ---- Q fragments: direct global load + fp16 2-way split into registers ----
    h8_t qfh[6], qfl[6];
    {
        const float* qrow = q + ((size_t)(b * S_ + s0 + 16 * mt + ln) * H_ + h) * QKD;
#pragma unroll
        for (int kk = 0; kk < 6; ++kk) {
            float4 x0 = *(const float4*)(qrow + kk * 32 + quad * 8);
            float4 x1 = *(const float4*)(qrow + kk * 32 + quad * 8 + 4);
            float v[8] = {x0.x, x0.y, x0.z, x0.w, x1.x, x1.y, x1.z, x1.w};
#pragma unroll
            for (int j = 0; j < 8; ++j) {
                _Float16 hh = (_Float16)v[j];
                qfh[kk][j] = hh;
                qfl[kk][j] = (_Float16)(v[j] - (float)hh);
            }
        }
    }

    // ---- score accumulators in registers: accs[chunk][ntile] ----
    f4_t accs[4][2];
#pragma unroll
    for (int c = 0; c < 4; ++c)
#pragma unroll
        for (int i = 0; i < 2; ++i) accs[c][i] = (f4_t){0.f, 0.f, 0.f, 0.f};

#pragma unroll
    for (int c = 0; c < 4; ++c) {
        // stage K chunk: 64 rows x 192 x 2 planes
#pragma unroll
        for (int u = 0; u < 6; ++u) {
            int f = t + u * 512;
            int p = f / 1536, rem = f % 1536;
            int row = rem / 24, sg = rem % 24;
            int gn = c * 64 + row;
            uint4 val = make_uint4(0, 0, 0, 0);
            const unsigned short* src = p ? kl_g : kh_g;
            if (gn < NBLK)
                val = *(const uint4*)(src + ((size_t)bh * NBLK + gn) * QKD + sg * 8);
            *(uint4*)((p ? kstl : ksth) + row * 196 + sg * 8) = val;
        }
        __syncthreads();
#pragma unroll
        for (int kk = 0; kk < 6; ++kk) {
#pragma unroll
            for (int i = 0; i < 2; ++i) {
                const unsigned short* bb = (nhalf * 32 + i * 16 + ln) * 196 + kk * 32 + quad * 8 + ksth;
                h8_t bhf = *(const h8_t*)bb;
                h8_t blf = *(const h8_t*)(bb + 12544);
                accs[c][i] = MFH(qfh[kk], bhf, accs[c][i]);
                accs[c][i] = MFH(qfh[kk], blf, accs[c][i]);
                accs[c][i] = MFH(qfl[kk], bhf, accs[c][i]);
            }
        }
        __syncthreads();   // readers done before next chunk restage
    }

    // ---- in-register masked softmax over each wave's 16 rows x 128 cols ----
    int nv[4];
    float mrow[4], srow[4], inv[4];
#pragma unroll
    for (int r = 0; r < 4; ++r) {
        int s = s0 + 16 * mt + quad * 4 + r;
        nv[r] = (s >= 31) ? (((s - 31) >> 4) + 1) : 0;
        mrow[r] = -INFINITY;
    }
#pragma unroll
    for (int c = 0; c < 4; ++c)
#pragma unroll
        for (int i = 0; i < 2; ++i) {
            int col = c * 64 + nhalf * 32 + i * 16 + ln;
#pragma unroll
            for (int r = 0; r < 4; ++r) {
                float v = (col < nv[r]) ? accs[c][i][r] * SCALEF : -INFINITY;
                accs[c][i][r] = v;
                mrow[r] = fmaxf(mrow[r], v);
            }
        }
#pragma unroll
    for (int r = 0; r < 4; ++r) {
#pragma unroll
        for (int off = 1; off < 16; off <<= 1)
            mrow[r] = fmaxf(mrow[r], __shfl_xor(mrow[r], off, 64));
    }
    if (ln == 0) {
#pragma unroll
        for (int r = 0; r < 4; ++r)
            rowred[((0 * 2 + nhalf) * 4 + mt) * 16 + quad * 4 + r] = mrow[r];
    }
    __syncthreads();
#pragma unroll
    for (int r = 0; r < 4; ++r) {
        int ri = mt * 16 + quad * 4 + r;
        mrow[r] = fmaxf(rowred[(0 * 2 + 0) * 64 + ri], rowred[(0 * 2 + 1) * 64 + ri]);
        srow[r] = 0.f;
    }
#pragma unroll
    for (int c = 0; c < 4; ++c)
#pragma unroll
        for (int i = 0; i < 2; ++i) {
            int col = c * 64 + nhalf * 32 + i * 16 + ln;
#pragma unroll
            for (int r = 0; r < 4; ++r) {
                float e = (col < nv[r]) ? __expf(accs[c][i][r] - mrow[r]) : 0.f;
                accs[c][i][r] = e;
                srow[r] += e;
            }
        }
#pragma unroll
    for (int r = 0; r < 4; ++r) {
#pragma unroll
        for (int off = 1; off < 16; off <<= 1)
            srow[r] += __shfl_xor(srow[r], off, 64);
    }
    if (ln == 0) {
#pragma unroll
        for (int r = 0; r < 4; ++r)
            rowred[((1 * 2 + nhalf) * 4 + mt) * 16 + quad * 4 + r] = srow[r];
    }
    __syncthreads();
#pragma unroll
    for (int r = 0; r < 4; ++r) {
        int ri = mt * 16 + quad * 4 + r;
        float tot = rowred[(1 * 2 + 0) * 64 + ri] + rowred[(1 * 2 + 1) * 64 + ri];
        inv[r] = (tot > 0.f) ? (1.0f / tot) : 0.f;
    }
    __syncthreads();   // rowred reads done; scb/vTl regions may be overwritten

    // ---- probs: scb fp16 + p_agg fp32 atomicMax ----
#pragma unroll
    for (int c = 0; c < 4; ++c)
#pragma unroll
        for (int i = 0; i < 2; ++i) {
            int col = c * 64 + nhalf * 32 + i * 16 + ln;
#pragma unroll
            for (int r = 0; r < 4; ++r) {
                int row = 16 * mt + quad * 4 + r;
                float p = accs[c][i][r] * inv[r];
                scb[row * 264 + col] = f2h(p);
                if (col < nv[r])
                    atomicMax(&p_agg[((size_t)(b * S_ + s0 + row)) * NBLK + col],
                              __float_as_uint(p));
            }
        }

    // ---- PV: O(64x128) = P(64x256) @ V, two 128-k halves ----
    const int mt2 = wv & 3, jgrp = wv >> 2;
    f4_t oacc[4];
#pragma unroll
    for (int jj = 0; jj < 4; ++jj) oacc[jj] = (f4_t){0.f, 0.f, 0.f, 0.f};
#pragma unroll
    for (int kh2 = 0; kh2 < 2; ++kh2) {
        __syncthreads();   // scb writes (kh2=0) / prior MFMA reads (kh2=1) done
#pragma unroll
        for (int u = 0; u < 4; ++u) {
            int f = t + u * 512;
            int j = f >> 4, sg = f & 15;
            *(uint4*)(vTl + j * 136 + sg * 8) =
                *(const uint4*)(vT_g + ((size_t)bh * VD + j) * 256 + kh2 * 128 + sg * 8);
        }
        __syncthreads();
#pragma unroll
        for (int kk = 0; kk < 4; ++kk) {
            h8_t pf = *(const h8_t*)(scb + (16 * mt2 + ln) * 264 + kh2 * 128 + kk * 32 + quad * 8);
#pragma unroll
            for (int jj = 0; jj < 4; ++jj) {
                h8_t vf = *(const h8_t*)(vTl + ((jgrp * 4 + jj) * 16 + ln) * 136 + kk * 32 + quad * 8);
                oacc[jj] = MFH(pf, vf, oacc[jj]);
            }
        }
    }
#pragma unroll
    for (int jj = 0; jj < 4; ++jj) {
#pragma unroll
        for (int r = 0; r < 4; ++r) {
            int row = 16 * mt2 + quad * 4 + r;
            o[((size_t)(b * S_ + s0 + row)) * 2048 + h * VD + (jgrp * 4 + jj) * 16 + ln] =
                oacc[jj][r];
        }
    }
}

// ---------------------------------------------------------------------------
// G4: slc + forced/causal + top-16.  (unchanged)
// ---------------------------------------------------------------------------
__global__ __launch_bounds__(256) void g4_topk(const float* __restrict__ p_agg,
                                               float* __restrict__ outI) {
    const int gid  = blockIdx.x * 256 + threadIdx.x;
    const int w    = gid >> 6;          // = b*S + s
    const int lane = threadIdx.x & 63;  // = j
    const int s    = w & (S_ - 1);
    const float* pa = p_agg + (size_t)w * NBLK;
    const int j = lane;
    float slc = 0.f;
    int nlo = 4 * j - 1; if (nlo < 0) nlo = 0;
    int nhi = 4 * j + 3; if (nhi > NBLK - 1) nhi = NBLK - 1;
    for (int n = nlo; n <= nhi; ++n) slc += pa[n];
    const int jt = s >> 6;
    float val;
    if (j <= jt) val = ((j < 1) || (j >= jt - 1)) ? BIGF : slc;
    else         val = -BIGF;
    bool taken = false;
    float* dst = outI + (size_t)w * TOPKN;
    for (int kk = 0; kk < TOPKN; ++kk) {
        float v = taken ? -INFINITY : val;
        float m = v;
#pragma unroll
        for (int off = 32; off; off >>= 1) m = fmaxf(m, __shfl_xor(m, off, 64));
        unsigned long long msk = __ballot((!taken) && (val == m));
        int first = __ffsll(msk) - 1;
        if (lane == first) taken = true;
        if (lane == kk) dst[kk] = (m <= -BIGF * 0.5f) ? -1.0f : (float)first;
    }
}

// ---------------------------------------------------------------------------
extern "C" void kernel_launch(void* const* d_in, const int* in_sizes, int n_in,
                              void* d_out, int out_size, void* d_ws, size_t ws_size,
                              hipStream_t stream) {
    const float* q         = (const float*)d_in[0];
    const float* kv_lora   = (const float*)d_in[1];
    const float* k_pe      = (const float*)d_in[2];
    const float* W_cmp_kv  = (const float*)d_in[3];
    const float* W_cmp_kpe = (const float*)d_in[4];
    const float* W_kv_b    = (const float*)d_in[5];
    float* out = (float*)d_out;
    char* W = (char*)d_ws;

    // byte offsets (all 16-aligned)
    float* cmp_kv        = (float*)W;                         // 1,044,480 B
    float* cmp_pe        = (float*)(W + 1044480);             //   130,560 B
    unsigned int* p_agg  = (unsigned int*)(W + 1175040);      // 8,355,840 B
    unsigned short* kh_g = (unsigned short*)(W + 9530880);    // 3,133,440 B
    unsigned short* kl_g = (unsigned short*)(W + 12664320);   // 3,133,440 B
    unsigned short* vT_g = (unsigned short*)(W + 15797760);   // 2,097,152 B
                                                              // end 17,894,912 B

    hipMemsetAsync(cmp_kv, 0, (size_t)1044480, stream);
    hipMemsetAsync(p_agg, 0, (size_t)8355840, stream);

    g1_cmpkv  <<<dim3(4, 8, 16), 256, 0, stream>>>(kv_lora, W_cmp_kv, cmp_kv);
    g1b_cmppe <<<dim3(128),      256, 0, stream>>>(k_pe, W_cmp_kpe, cmp_pe);
    g2_kvb    <<<dim3(8, 64),    256, 0, stream>>>(cmp_kv, W_kv_b, kh_g, kl_g, vT_g);
    g2b_pefill<<<dim3(2040),     256, 0, stream>>>(cmp_pe, kh_g, kl_g);
    g3_attn   <<<dim3(64, 32),   512, 0, stream>>>(q, kh_g, kl_g, vT_g, out, p_agg);
    g4_topk   <<<dim3(2048),     256, 0, stream>>>((const float*)p_agg, out + 16777216);
}